// Round 3
// baseline (676.941 us; speedup 1.0000x reference)
//
#include <hip/hip_runtime.h>
#include <stdint.h>

#define Bsz 4
#define Nn 4096
#define Dd 512
#define CAP 512
#define TH0 0.08f

typedef unsigned short u16;
typedef __attribute__((ext_vector_type(8))) _Float16 f16x8;
typedef __attribute__((ext_vector_type(4))) float f32x4;
typedef __attribute__((address_space(3))) uint32_t lds_as;
typedef __attribute__((address_space(1))) const uint32_t gbl_as;

__device__ __forceinline__ u16 f16_of(float v) {
  _Float16 h = (_Float16)v;           // v_cvt_f16_f32, RN
  return __builtin_bit_cast(u16, h);
}
__device__ __forceinline__ float f_of_f16(u16 u) {
  return (float)__builtin_bit_cast(_Float16, u);   // v_cvt_f32_f16
}

// ---------------- K1: normalize rows -> fp16, store rinv; zero cnt/flagc ----------------
__global__ __launch_bounds__(128) void prep_kernel(const float* __restrict__ x,
                                                   float* __restrict__ rinv,
                                                   u16* __restrict__ xh,
                                                   uint32_t* __restrict__ cnt,
                                                   uint32_t* __restrict__ flagc) {
  int row = blockIdx.x;   // B*N rows
  int t = threadIdx.x;    // 128 threads, one float4 each
  if (t == 0) { cnt[row] = 0; if (row == 0) flagc[0] = 0; }
  const float4* xr = (const float4*)(x + (size_t)row * Dd);
  float4 v = xr[t];
  float s = v.x * v.x + v.y * v.y + v.z * v.z + v.w * v.w;
  for (int o = 32; o > 0; o >>= 1) s += __shfl_down(s, o, 64);
  __shared__ float ls[2];
  if ((t & 63) == 0) ls[t >> 6] = s;
  __syncthreads();
  float ri = 1.0f / fmaxf(sqrtf(ls[0] + ls[1]), 1e-12f);
  if (t == 0) rinv[row] = ri;
  u16 h0 = f16_of(v.x * ri), h1 = f16_of(v.y * ri);
  u16 h2 = f16_of(v.z * ri), h3 = f16_of(v.w * ri);
  uint2 hp;
  hp.x = (uint32_t)h0 | ((uint32_t)h1 << 16);
  hp.y = (uint32_t)h2 | ((uint32_t)h3 << 16);
  *(uint2*)(xh + (size_t)row * Dd + t * 4) = hp;
}

// ---------------- K2: fp16 symmetric MFMA GEMM + fused candidate extraction ----------------
// Upper-triangle tiles only; no mirror write. Candidates (fp32 v > TH0) appended to
// per-row global lists, packed as (f16val<<16)|(col^0xFFF) so u32-desc == val-desc,idx-asc.
__global__ __launch_bounds__(256) void gemm_sym(const u16* __restrict__ xh,
                                                u16* __restrict__ simb,
                                                uint32_t* __restrict__ cnt,
                                                uint32_t* __restrict__ lists) {
  __shared__ __align__(16) u16 lds[2 * 128 * 64];   // 32 KB
  int b = blockIdx.y;
  int p0 = blockIdx.x;
  int p = (p0 & 7) * 66 + (p0 >> 3);   // bijective XCD swizzle (528 = 8*66)
  const int T = Nn / 128;
  int ti = 0;
  while (p >= T - ti) { p -= T - ti; ti++; }
  int tj = ti + p;
  int ri0 = ti * 128, rj0 = tj * 128;
  int tid = threadIdx.x, wid = tid >> 6, lane = tid & 63;
  int wr = (wid >> 1) * 64, wc = (wid & 1) * 64;   // wave's 64x64 quadrant
  int frow = lane & 15, kg = lane >> 4;

  // staging role: tile = wid>>1 (0=A rows@ri0, 1=B rows@rj0), half = wid&1
  int tile = wid >> 1, half = wid & 1;
  int rbase = tile ? rj0 : ri0;
  const u16* sb = xh + ((size_t)b * Nn + rbase + half * 64 + (lane >> 3)) * Dd
                     + (((lane & 7) ^ (lane >> 3)) * 8);
  u16* tb = &lds[tile * 8192 + half * 4096];   // wave-uniform LDS base; HW adds lane*16B

  f32x4 acc[4][4];
#pragma unroll
  for (int mt = 0; mt < 4; mt++)
#pragma unroll
    for (int nt = 0; nt < 4; nt++) acc[mt][nt] = (f32x4){0.f, 0.f, 0.f, 0.f};

  for (int k0 = 0; k0 < Dd; k0 += 64) {
    __syncthreads();
#pragma unroll
    for (int i = 0; i < 8; i++) {
      __builtin_amdgcn_global_load_lds((gbl_as*)(sb + (size_t)i * 8 * Dd + k0),
                                       (lds_as*)(tb + i * 512), 16, 0, 0);
    }
    __syncthreads();   // drains vmcnt -> staging visible
#pragma unroll
    for (int kk = 0; kk < 2; kk++) {
      f16x8 bfr[4];
#pragma unroll
      for (int nt = 0; nt < 4; nt++) {
        int rB = wc + nt * 16 + frow;
        int ps = (kk * 4 + kg) ^ (rB & 7);
        bfr[nt] = *(const f16x8*)&lds[8192 + rB * 64 + ps * 8];
      }
#pragma unroll
      for (int mt = 0; mt < 4; mt++) {
        int rA = wr + mt * 16 + frow;
        int ps = (kk * 4 + kg) ^ (rA & 7);
        f16x8 af = *(const f16x8*)&lds[rA * 64 + ps * 8];
#pragma unroll
        for (int nt = 0; nt < 4; nt++)
          acc[mt][nt] = __builtin_amdgcn_mfma_f32_16x16x32_f16(af, bfr[nt], acc[mt][nt], 0, 0, 0);
      }
    }
  }

  // ---- epilogue: upper-tile store + candidate extraction (no LDS use, no barrier) ----
  u16* ob = simb + (size_t)b * Nn * Nn;
  uint32_t grb = (uint32_t)b * Nn;
  bool offdiag = (ti != tj);
#pragma unroll
  for (int mt = 0; mt < 4; mt++) {
    int R0 = wr + mt * 16 + (lane >> 4) * 4;
    int rowg0 = ri0 + R0;
#pragma unroll
    for (int nt = 0; nt < 4; nt++) {
      int colg = rj0 + wc + nt * 16 + frow;
      float vv[4] = {acc[mt][nt].x, acc[mt][nt].y, acc[mt][nt].z, acc[mt][nt].w};
#pragma unroll
      for (int e = 0; e < 4; e++) {
        u16 u = f16_of(vv[e]);
        ob[(size_t)(rowg0 + e) * Nn + colg] = u;
        if (vv[e] > TH0) {
          uint32_t r1 = grb + (uint32_t)(rowg0 + e);
          uint32_t pos = atomicAdd(&cnt[r1], 1u);
          if (pos < CAP)
            lists[(size_t)r1 * CAP + pos] =
                ((uint32_t)u << 16) | ((uint32_t)colg ^ 0xFFFu);
          if (offdiag) {
            uint32_t r2 = grb + (uint32_t)colg;
            uint32_t pos2 = atomicAdd(&cnt[r2], 1u);
            if (pos2 < CAP)
              lists[(size_t)r2 * CAP + pos2] =
                  ((uint32_t)u << 16) | ((uint32_t)(rowg0 + e) ^ 0xFFFu);
          }
        }
      }
    }
  }
}

// ---------------- K3: exact rank over candidate list + fp32 band refinement ----------------
__global__ __launch_bounds__(256) void rank_kernel(const uint32_t* __restrict__ cnt,
                                                   const uint32_t* __restrict__ lists,
                                                   const float* __restrict__ x,
                                                   const float* __restrict__ rinv,
                                                   uint32_t* __restrict__ bm,
                                                   uint32_t* __restrict__ flagc,
                                                   uint32_t* __restrict__ flagl) {
  int row = blockIdx.x;   // global row in [0, B*N)
  int t = threadIdx.x;    // 256
  int L = (int)cnt[row];
  if (L < 32 || L > CAP) {            // guarantees violated -> exact fallback
    if (t == 0) { uint32_t p = atomicAdd(flagc, 1u); flagl[p] = (uint32_t)row; }
    return;
  }
  __shared__ uint32_t pk[CAP];
  __shared__ uint32_t sSp;
  __shared__ uint32_t lmask[128];
  __shared__ int red[4];
  __shared__ int bandIdx[128];
  __shared__ float bandV[128];
  __shared__ int bandCnt;
  for (int e = t; e < L; e += 256) pk[e] = lists[(size_t)row * CAP + e];
  if (t < 128) lmask[t] = 0;
  if (t == 0) bandCnt = 0;
  __syncthreads();

  // exact rank; rank-31 packed value is the 32nd largest (val desc, idx asc)
  for (int e = t; e < L; e += 256) {
    uint32_t pe = pk[e];
    int rank = 0;
    for (int q = 0; q < L; q++) rank += (pk[q] > pe) ? 1 : 0;
    if (rank == 31) sSp = pe;
  }
  __syncthreads();
  uint32_t Sp = sSp;
  float Sv = f_of_f16((u16)(Sp >> 16));
  float eb = fmaxf(3e-4f, Sv * 1e-3f);
  float hiT = Sv + eb, loT = Sv - eb;
  if (loT <= TH0 + 2e-3f) {           // band may extend below list threshold -> fallback
    if (t == 0) { uint32_t p = atomicAdd(flagc, 1u); flagl[p] = (uint32_t)row; }
    return;
  }

  // classify list entries
  int aCnt = 0;
  for (int e = t; e < L; e += 256) {
    uint32_t pe = pk[e];
    float v = f_of_f16((u16)(pe >> 16));
    int col = (int)((pe & 0xFFFu) ^ 0xFFFu);
    if (v > hiT) {
      atomicOr(&lmask[col >> 5], 1u << (col & 31));
      aCnt++;
    } else if (v >= loT) {
      int s = atomicAdd(&bandCnt, 1);
      if (s < 128) bandIdx[s] = col;
    }
  }
  for (int o = 32; o > 0; o >>= 1) aCnt += __shfl_down(aCnt, o, 64);
  if ((t & 63) == 0) red[t >> 6] = aCnt;
  __syncthreads();
  int A = red[0] + red[1] + red[2] + red[3];   // robustly above (<=31 by rank invariant)
  int BC = bandCnt; if (BC > 128) BC = 128;
  int need = 32 - A;                            // >=1
  bool heavy = (BC > need);
  if (heavy) {
    // recompute band sims with exact fp32 chain
    const float* xn = x + (size_t)row * Dd;
    float ra = rinv[row];
    int bb = row >> 12;
    const float* xbb = x + ((size_t)bb << 12) * Dd;
    for (int s = t; s < BC; s += 256) {
      int m = bandIdx[s];
      const float* xm = xbb + (size_t)m * Dd;
      float dot = 0.f;
      for (int k = 0; k < Dd; k += 4) {
        float4 a4 = *(const float4*)(xn + k);
        float4 b4 = *(const float4*)(xm + k);
        dot = fmaf(a4.x, b4.x, dot);
        dot = fmaf(a4.y, b4.y, dot);
        dot = fmaf(a4.z, b4.z, dot);
        dot = fmaf(a4.w, b4.w, dot);
      }
      bandV[s] = (dot * ra) * rinv[((size_t)bb << 12) + m];
    }
  }
  __syncthreads();
  if (t == 0) {
    if (!heavy) {
      for (int s = 0; s < BC; s++) {
        int gi = bandIdx[s];
        lmask[gi >> 5] |= 1u << (gi & 31);
      }
    } else {
      for (int s = 0; s < need; s++) {   // top-need by (value desc, index asc)
        float bv = -1e30f; int bidx = 0x7FFFFFFF, bs = -1;
        for (int q = 0; q < BC; q++) {
          int gi = bandIdx[q];
          if (gi < 0) continue;
          float v = bandV[q];
          if (v > bv || (v == bv && gi < bidx)) { bv = v; bidx = gi; bs = q; }
        }
        if (bs < 0) break;
        bandIdx[bs] = -1;
        lmask[bidx >> 5] |= 1u << (bidx & 31);
      }
    }
  }
  __syncthreads();
  if (t < 128) bm[(size_t)row * 128 + t] = lmask[t];
}

// ---------------- K3b: exact fp32 fallback for flagged rows (normally empty) ----------------
__global__ __launch_bounds__(256) void fallback_kernel(const uint32_t* __restrict__ flagc,
                                                       const uint32_t* __restrict__ flagl,
                                                       const float* __restrict__ x,
                                                       const float* __restrict__ rinv,
                                                       uint32_t* __restrict__ bm) {
  __shared__ float sv[Nn];            // 16 KB
  __shared__ uint32_t lmask[128];
  __shared__ float wbV[4];
  __shared__ int wbI[4];
  int nf = (int)flagc[0];
  int t = threadIdx.x;
  for (int f = blockIdx.x; f < nf; f += gridDim.x) {
    int row = (int)flagl[f];
    int bb = row >> 12;
    const float* xr = x + (size_t)row * Dd;
    const float* xb = x + ((size_t)bb << 12) * Dd;
    float ra = rinv[row];
    if (t < 128) lmask[t] = 0;
    for (int j = t; j < Nn; j += 256) {
      const float* xj = xb + (size_t)j * Dd;
      float dot = 0.f;
      for (int k = 0; k < Dd; k += 4) {
        float4 a4 = *(const float4*)(xr + k);
        float4 b4 = *(const float4*)(xj + k);
        dot = fmaf(a4.x, b4.x, dot);
        dot = fmaf(a4.y, b4.y, dot);
        dot = fmaf(a4.z, b4.z, dot);
        dot = fmaf(a4.w, b4.w, dot);
      }
      sv[j] = (dot * ra) * rinv[((size_t)bb << 12) + j];
    }
    __syncthreads();
    for (int r = 0; r < 32; r++) {     // 32 rounds of block argmax (val desc, idx asc)
      float bv = -1e30f; int bi = Nn;
      for (int j = t; j < Nn; j += 256) {
        float v = sv[j];
        if (v > bv || (v == bv && j < bi)) { bv = v; bi = j; }
      }
      for (int o = 32; o > 0; o >>= 1) {
        float ov = __shfl_down(bv, o, 64);
        int oi = __shfl_down(bi, o, 64);
        if (ov > bv || (ov == bv && oi < bi)) { bv = ov; bi = oi; }
      }
      if ((t & 63) == 0) { wbV[t >> 6] = bv; wbI[t >> 6] = bi; }
      __syncthreads();
      if (t == 0) {
        float fv = wbV[0]; int fi = wbI[0];
        for (int w = 1; w < 4; w++)
          if (wbV[w] > fv || (wbV[w] == fv && wbI[w] < fi)) { fv = wbV[w]; fi = wbI[w]; }
        sv[fi] = -2e30f;
        lmask[fi >> 5] |= 1u << (fi & 31);
      }
      __syncthreads();
    }
    if (t < 128) bm[(size_t)row * 128 + t] = lmask[t];
    __syncthreads();
  }
}

// ---------------- K4: masked symmetrize, fp16 sim -> fp32 out; exact 1.0 diagonal ----------------
__global__ __launch_bounds__(256) void finalize_kernel(const u16* __restrict__ simb,
                                                       float* __restrict__ out,
                                                       const uint32_t* __restrict__ bm) {
  __shared__ float Tt[64][65];
  __shared__ uint32_t kA[64][2], kB[64][2];
  int b = blockIdx.y;
  int p = blockIdx.x;             // 0..2079 (T=64)
  const int T = Nn / 64;
  int ti = 0;
  while (p >= T - ti) { p -= T - ti; ti++; }
  int tj = ti + p;
  int ri0 = ti * 64, rj0 = tj * 64;
  int t = threadIdx.x;
  const uint32_t* bmb = bm + (size_t)b * Nn * 128;
  if (t < 128) {
    kA[t >> 1][t & 1] = bmb[(size_t)(ri0 + (t >> 1)) * 128 + (rj0 >> 5) + (t & 1)];
  } else {
    int tt = t - 128;
    kB[tt >> 1][tt & 1] = bmb[(size_t)(rj0 + (tt >> 1)) * 128 + (ri0 >> 5) + (tt & 1)];
  }
  __syncthreads();
  const u16* sbase = simb + (size_t)b * Nn * Nn;
  float* ob = out + (size_t)b * Nn * Nn;
  bool diag = (ti == tj);
#pragma unroll
  for (int it = 0; it < 2; it++) {
    int pq = it * 256 + t;          // 512 ushort8-units in the 64x64 tile
    int nl = pq >> 3;
    int ml = (pq & 7) * 8;
    uint4 u = *(const uint4*)(sbase + (size_t)(ri0 + nl) * Nn + rj0 + ml);
    float s0 = f_of_f16((u16)(u.x & 0xFFFFu)), s1 = f_of_f16((u16)(u.x >> 16));
    float s2 = f_of_f16((u16)(u.y & 0xFFFFu)), s3 = f_of_f16((u16)(u.y >> 16));
    float s4 = f_of_f16((u16)(u.z & 0xFFFFu)), s5 = f_of_f16((u16)(u.z >> 16));
    float s6 = f_of_f16((u16)(u.w & 0xFFFFu)), s7 = f_of_f16((u16)(u.w >> 16));
    if (diag) {
      int d = nl - ml;   // element d of this chunk is the exact diagonal (sim(i,i)=1)
      s0 = (d == 0) ? 1.0f : s0;
      s1 = (d == 1) ? 1.0f : s1;
      s2 = (d == 2) ? 1.0f : s2;
      s3 = (d == 3) ? 1.0f : s3;
      s4 = (d == 4) ? 1.0f : s4;
      s5 = (d == 5) ? 1.0f : s5;
      s6 = (d == 6) ? 1.0f : s6;
      s7 = (d == 7) ? 1.0f : s7;
    }
    uint32_t ka = kA[nl][ml >> 5] >> (ml & 31);   // 8 bits, same word (ml%32 in {0,8,16,24})
    uint32_t nw = nl >> 5, nb = nl & 31;
    float4 v0, v1;
    v0.x = 0.5f * s0 * (float)(((ka >> 0) & 1u) + ((kB[ml + 0][nw] >> nb) & 1u));
    v0.y = 0.5f * s1 * (float)(((ka >> 1) & 1u) + ((kB[ml + 1][nw] >> nb) & 1u));
    v0.z = 0.5f * s2 * (float)(((ka >> 2) & 1u) + ((kB[ml + 2][nw] >> nb) & 1u));
    v0.w = 0.5f * s3 * (float)(((ka >> 3) & 1u) + ((kB[ml + 3][nw] >> nb) & 1u));
    v1.x = 0.5f * s4 * (float)(((ka >> 4) & 1u) + ((kB[ml + 4][nw] >> nb) & 1u));
    v1.y = 0.5f * s5 * (float)(((ka >> 5) & 1u) + ((kB[ml + 5][nw] >> nb) & 1u));
    v1.z = 0.5f * s6 * (float)(((ka >> 6) & 1u) + ((kB[ml + 6][nw] >> nb) & 1u));
    v1.w = 0.5f * s7 * (float)(((ka >> 7) & 1u) + ((kB[ml + 7][nw] >> nb) & 1u));
    size_t addr = (size_t)(ri0 + nl) * Nn + rj0 + ml;
    *(float4*)(ob + addr) = v0;
    *(float4*)(ob + addr + 4) = v1;
    Tt[ml + 0][nl] = v0.x; Tt[ml + 1][nl] = v0.y; Tt[ml + 2][nl] = v0.z; Tt[ml + 3][nl] = v0.w;
    Tt[ml + 4][nl] = v1.x; Tt[ml + 5][nl] = v1.y; Tt[ml + 6][nl] = v1.z; Tt[ml + 7][nl] = v1.w;
  }
  if (ti != tj) {
    __syncthreads();
#pragma unroll
    for (int it = 0; it < 4; it++) {
      int pq = it * 256 + t;
      int nl = pq >> 4;
      int ml = (pq & 15) << 2;
      float4 v;
      v.x = Tt[nl][ml + 0]; v.y = Tt[nl][ml + 1];
      v.z = Tt[nl][ml + 2]; v.w = Tt[nl][ml + 3];
      *(float4*)(ob + (size_t)(rj0 + nl) * Nn + ri0 + ml) = v;
    }
  }
}

extern "C" void kernel_launch(void* const* d_in, const int* in_sizes, int n_in,
                              void* d_out, int out_size, void* d_ws, size_t ws_size,
                              hipStream_t stream) {
  const float* x = (const float*)d_in[0];
  float* out = (float*)d_out;
  // ws layout (16B-aligned):
  // rinv 64KB | bm 8MB | xh 16MB | simb 128MB | cnt 64KB | flagc 256B | flagl 64KB | lists 32MB
  char* base = (char*)d_ws;
  float* rinv = (float*)base;
  uint32_t* bm = (uint32_t*)(base + (1u << 16));
  u16* xh = (u16*)(base + (1u << 16) + (8u << 20));
  u16* simb = xh + (size_t)Bsz * Nn * Dd;
  uint32_t* cnt = (uint32_t*)((char*)simb + (size_t)Bsz * Nn * Nn * 2);
  uint32_t* flagc = cnt + (size_t)Bsz * Nn;
  uint32_t* flagl = flagc + 64;
  uint32_t* lists = flagl + (size_t)Bsz * Nn;

  prep_kernel<<<Bsz * Nn, 128, 0, stream>>>(x, rinv, xh, cnt, flagc);
  dim3 g2(528, Bsz);
  gemm_sym<<<g2, 256, 0, stream>>>(xh, simb, cnt, lists);
  rank_kernel<<<Bsz * Nn, 256, 0, stream>>>(cnt, lists, x, rinv, bm, flagc, flagl);
  fallback_kernel<<<64, 256, 0, stream>>>(flagc, flagl, x, rinv, bm);
  dim3 g4(2080, Bsz);
  finalize_kernel<<<g4, 256, 0, stream>>>(simb, out, bm);
}

// Round 4
// 485.437 us; speedup vs baseline: 1.3945x; 1.3945x over previous
//
#include <hip/hip_runtime.h>
#include <stdint.h>

#define Bsz 4
#define Nn 4096
#define Dd 512
#define CAP 512
#define TCAP 24
#define TH0 0.08f

typedef unsigned short u16;
typedef __attribute__((ext_vector_type(8))) _Float16 f16x8;
typedef __attribute__((ext_vector_type(4))) float f32x4;
typedef __attribute__((address_space(3))) uint32_t lds_as;
typedef __attribute__((address_space(1))) const uint32_t gbl_as;

__device__ __forceinline__ u16 f16_of(float v) {
  _Float16 h = (_Float16)v;           // v_cvt_f16_f32, RN
  return __builtin_bit_cast(u16, h);
}
__device__ __forceinline__ float f_of_f16(u16 u) {
  return (float)__builtin_bit_cast(_Float16, u);   // v_cvt_f32_f16
}

// ---------------- K1: normalize rows -> fp16, store rinv; zero cnt/flagc ----------------
__global__ __launch_bounds__(128) void prep_kernel(const float* __restrict__ x,
                                                   float* __restrict__ rinv,
                                                   u16* __restrict__ xh,
                                                   uint32_t* __restrict__ cnt,
                                                   uint32_t* __restrict__ flagc) {
  int row = blockIdx.x;   // B*N rows
  int t = threadIdx.x;    // 128 threads, one float4 each
  if (t == 0) { cnt[row] = 0; if (row == 0) flagc[0] = 0; }
  const float4* xr = (const float4*)(x + (size_t)row * Dd);
  float4 v = xr[t];
  float s = v.x * v.x + v.y * v.y + v.z * v.z + v.w * v.w;
  for (int o = 32; o > 0; o >>= 1) s += __shfl_down(s, o, 64);
  __shared__ float ls[2];
  if ((t & 63) == 0) ls[t >> 6] = s;
  __syncthreads();
  float ri = 1.0f / fmaxf(sqrtf(ls[0] + ls[1]), 1e-12f);
  if (t == 0) rinv[row] = ri;
  u16 h0 = f16_of(v.x * ri), h1 = f16_of(v.y * ri);
  u16 h2 = f16_of(v.z * ri), h3 = f16_of(v.w * ri);
  uint2 hp;
  hp.x = (uint32_t)h0 | ((uint32_t)h1 << 16);
  hp.y = (uint32_t)h2 | ((uint32_t)h3 << 16);
  *(uint2*)(xh + (size_t)row * Dd + t * 4) = hp;
}

// ---------------- K2: fp16 symmetric MFMA GEMM + LDS-aggregated candidate extraction ----------------
// Upper-triangle tiles only; no mirror simb write. Candidates (fp32 v > TH0) are
// aggregated per local row/col in LDS (aliasing the dead staging buffer), then
// flushed with ONE global atomicAdd per list + small bulk write. Packed entry:
// (f16val<<16)|(col^0xFFF) so u32-desc == (val desc, idx asc).
__global__ __launch_bounds__(256) void gemm_sym(const u16* __restrict__ xh,
                                                u16* __restrict__ simb,
                                                uint32_t* __restrict__ cnt,
                                                uint32_t* __restrict__ lists) {
  __shared__ __align__(16) u16 lds[2 * 128 * 64];   // 32 KB; epilogue reuses as cand agg
  int b = blockIdx.y;
  int p0 = blockIdx.x;
  int p = (p0 & 7) * 66 + (p0 >> 3);   // bijective XCD swizzle (528 = 8*66)
  const int T = Nn / 128;
  int ti = 0;
  while (p >= T - ti) { p -= T - ti; ti++; }
  int tj = ti + p;
  int ri0 = ti * 128, rj0 = tj * 128;
  int tid = threadIdx.x, wid = tid >> 6, lane = tid & 63;
  int wr = (wid >> 1) * 64, wc = (wid & 1) * 64;   // wave's 64x64 quadrant
  int frow = lane & 15, kg = lane >> 4;

  // staging role: tile = wid>>1 (0=A rows@ri0, 1=B rows@rj0), half = wid&1
  int tile = wid >> 1, half = wid & 1;
  int rbase = tile ? rj0 : ri0;
  const u16* sb = xh + ((size_t)b * Nn + rbase + half * 64 + (lane >> 3)) * Dd
                     + (((lane & 7) ^ (lane >> 3)) * 8);
  u16* tb = &lds[tile * 8192 + half * 4096];   // wave-uniform LDS base; HW adds lane*16B

  f32x4 acc[4][4];
#pragma unroll
  for (int mt = 0; mt < 4; mt++)
#pragma unroll
    for (int nt = 0; nt < 4; nt++) acc[mt][nt] = (f32x4){0.f, 0.f, 0.f, 0.f};

  for (int k0 = 0; k0 < Dd; k0 += 64) {
    __syncthreads();
#pragma unroll
    for (int i = 0; i < 8; i++) {
      __builtin_amdgcn_global_load_lds((gbl_as*)(sb + (size_t)i * 8 * Dd + k0),
                                       (lds_as*)(tb + i * 512), 16, 0, 0);
    }
    __syncthreads();   // drains vmcnt -> staging visible
#pragma unroll
    for (int kk = 0; kk < 2; kk++) {
      f16x8 bfr[4];
#pragma unroll
      for (int nt = 0; nt < 4; nt++) {
        int rB = wc + nt * 16 + frow;
        int ps = (kk * 4 + kg) ^ (rB & 7);
        bfr[nt] = *(const f16x8*)&lds[8192 + rB * 64 + ps * 8];
      }
#pragma unroll
      for (int mt = 0; mt < 4; mt++) {
        int rA = wr + mt * 16 + frow;
        int ps = (kk * 4 + kg) ^ (rA & 7);
        f16x8 af = *(const f16x8*)&lds[rA * 64 + ps * 8];
#pragma unroll
        for (int nt = 0; nt < 4; nt++)
          acc[mt][nt] = __builtin_amdgcn_mfma_f32_16x16x32_f16(af, bfr[nt], acc[mt][nt], 0, 0, 0);
      }
    }
  }

  // ---- epilogue: upper-tile store + LDS candidate aggregation ----
  __syncthreads();   // all waves done with staging LDS; alias as agg buffers
  uint32_t* cntL = (uint32_t*)lds;            // [256] counters (rows 0-127, cols 128-255)
  uint32_t* candL = (uint32_t*)lds + 256;     // [256][TCAP] packed entries (24.5 KB)
  cntL[tid] = 0;
  __syncthreads();

  u16* ob = simb + (size_t)b * Nn * Nn;
  uint32_t grb = (uint32_t)b * Nn;
  bool offdiag = (ti != tj);
#pragma unroll
  for (int mt = 0; mt < 4; mt++) {
    int R0 = wr + mt * 16 + (lane >> 4) * 4;
    int rowg0 = ri0 + R0;
#pragma unroll
    for (int nt = 0; nt < 4; nt++) {
      int C = wc + nt * 16 + frow;
      int colg = rj0 + C;
      float vv[4] = {acc[mt][nt].x, acc[mt][nt].y, acc[mt][nt].z, acc[mt][nt].w};
#pragma unroll
      for (int e = 0; e < 4; e++) {
        u16 u = f16_of(vv[e]);
        ob[(size_t)(rowg0 + e) * Nn + colg] = u;
        if (vv[e] > TH0) {
          uint32_t s = atomicAdd(&cntL[R0 + e], 1u);
          if (s < TCAP)
            candL[(R0 + e) * TCAP + s] = ((uint32_t)u << 16) | ((uint32_t)colg ^ 0xFFFu);
          if (offdiag) {
            uint32_t s2 = atomicAdd(&cntL[128 + C], 1u);
            if (s2 < TCAP)
              candL[(128 + C) * TCAP + s2] = ((uint32_t)u << 16) | ((uint32_t)(rowg0 + e) ^ 0xFFFu);
          }
        }
      }
    }
  }
  __syncthreads();

  // ---- flush: thread tid owns list tid; one global atomic per non-empty list ----
  {
    uint32_t n = cntL[tid];
    bool isRow = tid < 128;
    if (!isRow && !offdiag) n = 0;           // col-lists unused on diagonal tiles
    if (n) {
      uint32_t grow = grb + (uint32_t)(isRow ? (ri0 + tid) : (rj0 + (tid - 128)));
      uint32_t add = (n > TCAP) ? 100000u : n;   // overflow poisons cnt -> fallback path
      uint32_t base = atomicAdd(&cnt[grow], add);
      uint32_t w = (n > TCAP) ? TCAP : n;
      if (base < CAP) {
        uint32_t lim = CAP - base;
        if (w > lim) w = lim;
        for (uint32_t j = 0; j < w; j++)
          lists[(size_t)grow * CAP + base + j] = candL[tid * TCAP + j];
      }
    }
  }
}

// ---------------- K3: exact rank over candidate list + fp32 band refinement ----------------
__global__ __launch_bounds__(256) void rank_kernel(const uint32_t* __restrict__ cnt,
                                                   const uint32_t* __restrict__ lists,
                                                   const float* __restrict__ x,
                                                   const float* __restrict__ rinv,
                                                   uint32_t* __restrict__ bm,
                                                   uint32_t* __restrict__ flagc,
                                                   uint32_t* __restrict__ flagl) {
  int row = blockIdx.x;   // global row in [0, B*N)
  int t = threadIdx.x;    // 256
  int L = (int)cnt[row];
  if (L < 32 || L > CAP) {            // guarantees violated -> exact fallback
    if (t == 0) { uint32_t p = atomicAdd(flagc, 1u); flagl[p] = (uint32_t)row; }
    return;
  }
  __shared__ uint32_t pk[CAP];
  __shared__ uint32_t sSp;
  __shared__ uint32_t lmask[128];
  __shared__ int red[4];
  __shared__ int bandIdx[128];
  __shared__ float bandV[128];
  __shared__ int bandCnt;
  for (int e = t; e < L; e += 256) pk[e] = lists[(size_t)row * CAP + e];
  if (t < 128) lmask[t] = 0;
  if (t == 0) bandCnt = 0;
  __syncthreads();

  // exact rank; rank-31 packed value is the 32nd largest (val desc, idx asc)
  for (int e = t; e < L; e += 256) {
    uint32_t pe = pk[e];
    int rank = 0;
    for (int q = 0; q < L; q++) rank += (pk[q] > pe) ? 1 : 0;
    if (rank == 31) sSp = pe;
  }
  __syncthreads();
  uint32_t Sp = sSp;
  float Sv = f_of_f16((u16)(Sp >> 16));
  float eb = fmaxf(3e-4f, Sv * 1e-3f);
  float hiT = Sv + eb, loT = Sv - eb;
  if (loT <= TH0 + 2e-3f) {           // band may extend below list threshold -> fallback
    if (t == 0) { uint32_t p = atomicAdd(flagc, 1u); flagl[p] = (uint32_t)row; }
    return;
  }

  // classify list entries
  int aCnt = 0;
  for (int e = t; e < L; e += 256) {
    uint32_t pe = pk[e];
    float v = f_of_f16((u16)(pe >> 16));
    int col = (int)((pe & 0xFFFu) ^ 0xFFFu);
    if (v > hiT) {
      atomicOr(&lmask[col >> 5], 1u << (col & 31));
      aCnt++;
    } else if (v >= loT) {
      int s = atomicAdd(&bandCnt, 1);
      if (s < 128) bandIdx[s] = col;
    }
  }
  for (int o = 32; o > 0; o >>= 1) aCnt += __shfl_down(aCnt, o, 64);
  if ((t & 63) == 0) red[t >> 6] = aCnt;
  __syncthreads();
  int A = red[0] + red[1] + red[2] + red[3];   // robustly above (<=31 by rank invariant)
  int BC = bandCnt; if (BC > 128) BC = 128;
  int need = 32 - A;                            // >=1
  bool heavy = (BC > need);
  if (heavy) {
    // recompute band sims with exact fp32 chain
    const float* xn = x + (size_t)row * Dd;
    float ra = rinv[row];
    int bb = row >> 12;
    const float* xbb = x + ((size_t)bb << 12) * Dd;
    for (int s = t; s < BC; s += 256) {
      int m = bandIdx[s];
      const float* xm = xbb + (size_t)m * Dd;
      float dot = 0.f;
      for (int k = 0; k < Dd; k += 4) {
        float4 a4 = *(const float4*)(xn + k);
        float4 b4 = *(const float4*)(xm + k);
        dot = fmaf(a4.x, b4.x, dot);
        dot = fmaf(a4.y, b4.y, dot);
        dot = fmaf(a4.z, b4.z, dot);
        dot = fmaf(a4.w, b4.w, dot);
      }
      bandV[s] = (dot * ra) * rinv[((size_t)bb << 12) + m];
    }
  }
  __syncthreads();
  if (t == 0) {
    if (!heavy) {
      for (int s = 0; s < BC; s++) {
        int gi = bandIdx[s];
        lmask[gi >> 5] |= 1u << (gi & 31);
      }
    } else {
      for (int s = 0; s < need; s++) {   // top-need by (value desc, index asc)
        float bv = -1e30f; int bidx = 0x7FFFFFFF, bs = -1;
        for (int q = 0; q < BC; q++) {
          int gi = bandIdx[q];
          if (gi < 0) continue;
          float v = bandV[q];
          if (v > bv || (v == bv && gi < bidx)) { bv = v; bidx = gi; bs = q; }
        }
        if (bs < 0) break;
        bandIdx[bs] = -1;
        lmask[bidx >> 5] |= 1u << (bidx & 31);
      }
    }
  }
  __syncthreads();
  if (t < 128) bm[(size_t)row * 128 + t] = lmask[t];
}

// ---------------- K3b: exact fp32 fallback for flagged rows (normally empty) ----------------
__global__ __launch_bounds__(256) void fallback_kernel(const uint32_t* __restrict__ flagc,
                                                       const uint32_t* __restrict__ flagl,
                                                       const float* __restrict__ x,
                                                       const float* __restrict__ rinv,
                                                       uint32_t* __restrict__ bm) {
  __shared__ float sv[Nn];            // 16 KB
  __shared__ uint32_t lmask[128];
  __shared__ float wbV[4];
  __shared__ int wbI[4];
  int nf = (int)flagc[0];
  int t = threadIdx.x;
  for (int f = blockIdx.x; f < nf; f += gridDim.x) {
    int row = (int)flagl[f];
    int bb = row >> 12;
    const float* xr = x + (size_t)row * Dd;
    const float* xb = x + ((size_t)bb << 12) * Dd;
    float ra = rinv[row];
    if (t < 128) lmask[t] = 0;
    for (int j = t; j < Nn; j += 256) {
      const float* xj = xb + (size_t)j * Dd;
      float dot = 0.f;
      for (int k = 0; k < Dd; k += 4) {
        float4 a4 = *(const float4*)(xr + k);
        float4 b4 = *(const float4*)(xj + k);
        dot = fmaf(a4.x, b4.x, dot);
        dot = fmaf(a4.y, b4.y, dot);
        dot = fmaf(a4.z, b4.z, dot);
        dot = fmaf(a4.w, b4.w, dot);
      }
      sv[j] = (dot * ra) * rinv[((size_t)bb << 12) + j];
    }
    __syncthreads();
    for (int r = 0; r < 32; r++) {     // 32 rounds of block argmax (val desc, idx asc)
      float bv = -1e30f; int bi = Nn;
      for (int j = t; j < Nn; j += 256) {
        float v = sv[j];
        if (v > bv || (v == bv && j < bi)) { bv = v; bi = j; }
      }
      for (int o = 32; o > 0; o >>= 1) {
        float ov = __shfl_down(bv, o, 64);
        int oi = __shfl_down(bi, o, 64);
        if (ov > bv || (ov == bv && oi < bi)) { bv = ov; bi = oi; }
      }
      if ((t & 63) == 0) { wbV[t >> 6] = bv; wbI[t >> 6] = bi; }
      __syncthreads();
      if (t == 0) {
        float fv = wbV[0]; int fi = wbI[0];
        for (int w = 1; w < 4; w++)
          if (wbV[w] > fv || (wbV[w] == fv && wbI[w] < fi)) { fv = wbV[w]; fi = wbI[w]; }
        sv[fi] = -2e30f;
        lmask[fi >> 5] |= 1u << (fi & 31);
      }
      __syncthreads();
    }
    if (t < 128) bm[(size_t)row * 128 + t] = lmask[t];
    __syncthreads();
  }
}

// ---------------- K4: masked symmetrize, fp16 sim -> fp32 out; exact 1.0 diagonal ----------------
__global__ __launch_bounds__(256) void finalize_kernel(const u16* __restrict__ simb,
                                                       float* __restrict__ out,
                                                       const uint32_t* __restrict__ bm) {
  __shared__ float Tt[64][65];
  __shared__ uint32_t kA[64][2], kB[64][2];
  int b = blockIdx.y;
  int p = blockIdx.x;             // 0..2079 (T=64)
  const int T = Nn / 64;
  int ti = 0;
  while (p >= T - ti) { p -= T - ti; ti++; }
  int tj = ti + p;
  int ri0 = ti * 64, rj0 = tj * 64;
  int t = threadIdx.x;
  const uint32_t* bmb = bm + (size_t)b * Nn * 128;
  if (t < 128) {
    kA[t >> 1][t & 1] = bmb[(size_t)(ri0 + (t >> 1)) * 128 + (rj0 >> 5) + (t & 1)];
  } else {
    int tt = t - 128;
    kB[tt >> 1][tt & 1] = bmb[(size_t)(rj0 + (tt >> 1)) * 128 + (ri0 >> 5) + (tt & 1)];
  }
  __syncthreads();
  const u16* sbase = simb + (size_t)b * Nn * Nn;
  float* ob = out + (size_t)b * Nn * Nn;
  bool diag = (ti == tj);
#pragma unroll
  for (int it = 0; it < 2; it++) {
    int pq = it * 256 + t;          // 512 ushort8-units in the 64x64 tile
    int nl = pq >> 3;
    int ml = (pq & 7) * 8;
    uint4 u = *(const uint4*)(sbase + (size_t)(ri0 + nl) * Nn + rj0 + ml);
    float s0 = f_of_f16((u16)(u.x & 0xFFFFu)), s1 = f_of_f16((u16)(u.x >> 16));
    float s2 = f_of_f16((u16)(u.y & 0xFFFFu)), s3 = f_of_f16((u16)(u.y >> 16));
    float s4 = f_of_f16((u16)(u.z & 0xFFFFu)), s5 = f_of_f16((u16)(u.z >> 16));
    float s6 = f_of_f16((u16)(u.w & 0xFFFFu)), s7 = f_of_f16((u16)(u.w >> 16));
    if (diag) {
      int d = nl - ml;   // element d of this chunk is the exact diagonal (sim(i,i)=1)
      s0 = (d == 0) ? 1.0f : s0;
      s1 = (d == 1) ? 1.0f : s1;
      s2 = (d == 2) ? 1.0f : s2;
      s3 = (d == 3) ? 1.0f : s3;
      s4 = (d == 4) ? 1.0f : s4;
      s5 = (d == 5) ? 1.0f : s5;
      s6 = (d == 6) ? 1.0f : s6;
      s7 = (d == 7) ? 1.0f : s7;
    }
    uint32_t ka = kA[nl][ml >> 5] >> (ml & 31);   // 8 bits, same word (ml%32 in {0,8,16,24})
    uint32_t nw = nl >> 5, nb = nl & 31;
    float4 v0, v1;
    v0.x = 0.5f * s0 * (float)(((ka >> 0) & 1u) + ((kB[ml + 0][nw] >> nb) & 1u));
    v0.y = 0.5f * s1 * (float)(((ka >> 1) & 1u) + ((kB[ml + 1][nw] >> nb) & 1u));
    v0.z = 0.5f * s2 * (float)(((ka >> 2) & 1u) + ((kB[ml + 2][nw] >> nb) & 1u));
    v0.w = 0.5f * s3 * (float)(((ka >> 3) & 1u) + ((kB[ml + 3][nw] >> nb) & 1u));
    v1.x = 0.5f * s4 * (float)(((ka >> 4) & 1u) + ((kB[ml + 4][nw] >> nb) & 1u));
    v1.y = 0.5f * s5 * (float)(((ka >> 5) & 1u) + ((kB[ml + 5][nw] >> nb) & 1u));
    v1.z = 0.5f * s6 * (float)(((ka >> 6) & 1u) + ((kB[ml + 6][nw] >> nb) & 1u));
    v1.w = 0.5f * s7 * (float)(((ka >> 7) & 1u) + ((kB[ml + 7][nw] >> nb) & 1u));
    size_t addr = (size_t)(ri0 + nl) * Nn + rj0 + ml;
    *(float4*)(ob + addr) = v0;
    *(float4*)(ob + addr + 4) = v1;
    Tt[ml + 0][nl] = v0.x; Tt[ml + 1][nl] = v0.y; Tt[ml + 2][nl] = v0.z; Tt[ml + 3][nl] = v0.w;
    Tt[ml + 4][nl] = v1.x; Tt[ml + 5][nl] = v1.y; Tt[ml + 6][nl] = v1.z; Tt[ml + 7][nl] = v1.w;
  }
  if (ti != tj) {
    __syncthreads();
#pragma unroll
    for (int it = 0; it < 4; it++) {
      int pq = it * 256 + t;
      int nl = pq >> 4;
      int ml = (pq & 15) << 2;
      float4 v;
      v.x = Tt[nl][ml + 0]; v.y = Tt[nl][ml + 1];
      v.z = Tt[nl][ml + 2]; v.w = Tt[nl][ml + 3];
      *(float4*)(ob + (size_t)(rj0 + nl) * Nn + ri0 + ml) = v;
    }
  }
}

extern "C" void kernel_launch(void* const* d_in, const int* in_sizes, int n_in,
                              void* d_out, int out_size, void* d_ws, size_t ws_size,
                              hipStream_t stream) {
  const float* x = (const float*)d_in[0];
  float* out = (float*)d_out;
  // ws layout (16B-aligned):
  // rinv 64KB | bm 8MB | xh 16MB | simb 128MB | cnt 64KB | flagc 256B | flagl 64KB | lists 32MB
  char* base = (char*)d_ws;
  float* rinv = (float*)base;
  uint32_t* bm = (uint32_t*)(base + (1u << 16));
  u16* xh = (u16*)(base + (1u << 16) + (8u << 20));
  u16* simb = xh + (size_t)Bsz * Nn * Dd;
  uint32_t* cnt = (uint32_t*)((char*)simb + (size_t)Bsz * Nn * Nn * 2);
  uint32_t* flagc = cnt + (size_t)Bsz * Nn;
  uint32_t* flagl = flagc + 64;
  uint32_t* lists = flagl + (size_t)Bsz * Nn;

  prep_kernel<<<Bsz * Nn, 128, 0, stream>>>(x, rinv, xh, cnt, flagc);
  dim3 g2(528, Bsz);
  gemm_sym<<<g2, 256, 0, stream>>>(xh, simb, cnt, lists);
  rank_kernel<<<Bsz * Nn, 256, 0, stream>>>(cnt, lists, x, rinv, bm, flagc, flagl);
  fallback_kernel<<<64, 256, 0, stream>>>(flagc, flagl, x, rinv, bm);
  dim3 g4(2080, Bsz);
  finalize_kernel<<<g4, 256, 0, stream>>>(simb, out, bm);
}

// Round 5
// 463.249 us; speedup vs baseline: 1.4613x; 1.0479x over previous
//
#include <hip/hip_runtime.h>
#include <stdint.h>

#define Bsz 4
#define Nn 4096
#define Dd 512
#define CAP 512
#define TCAP 24
#define TH0 0.08f

typedef unsigned short u16;
typedef __attribute__((ext_vector_type(8))) _Float16 f16x8;
typedef __attribute__((ext_vector_type(4))) float f32x4;
typedef __attribute__((address_space(3))) uint32_t lds_as;
typedef __attribute__((address_space(1))) const uint32_t gbl_as;

__device__ __forceinline__ u16 f16_of(float v) {
  _Float16 h = (_Float16)v;           // v_cvt_f16_f32, RN
  return __builtin_bit_cast(u16, h);
}
__device__ __forceinline__ float f_of_f16(u16 u) {
  return (float)__builtin_bit_cast(_Float16, u);   // v_cvt_f32_f16
}

// ---------------- K1: normalize rows -> fp16, store rinv; zero cnt/flagc ----------------
__global__ __launch_bounds__(128) void prep_kernel(const float* __restrict__ x,
                                                   float* __restrict__ rinv,
                                                   u16* __restrict__ xh,
                                                   uint32_t* __restrict__ cnt,
                                                   uint32_t* __restrict__ flagc) {
  int row = blockIdx.x;   // B*N rows
  int t = threadIdx.x;    // 128 threads, one float4 each
  if (t == 0) { cnt[row] = 0; if (row == 0) flagc[0] = 0; }
  const float4* xr = (const float4*)(x + (size_t)row * Dd);
  float4 v = xr[t];
  float s = v.x * v.x + v.y * v.y + v.z * v.z + v.w * v.w;
  for (int o = 32; o > 0; o >>= 1) s += __shfl_down(s, o, 64);
  __shared__ float ls[2];
  if ((t & 63) == 0) ls[t >> 6] = s;
  __syncthreads();
  float ri = 1.0f / fmaxf(sqrtf(ls[0] + ls[1]), 1e-12f);
  if (t == 0) rinv[row] = ri;
  u16 h0 = f16_of(v.x * ri), h1 = f16_of(v.y * ri);
  u16 h2 = f16_of(v.z * ri), h3 = f16_of(v.w * ri);
  uint2 hp;
  hp.x = (uint32_t)h0 | ((uint32_t)h1 << 16);
  hp.y = (uint32_t)h2 | ((uint32_t)h3 << 16);
  *(uint2*)(xh + (size_t)row * Dd + t * 4) = hp;
}

// ---------------- K2: fp16 symmetric MFMA GEMM, BK=32 double-buffered (T3-minimum) ----------------
// LDS: 2 buf x 2 tile x [128][32] fp16 = 32 KB. One barrier per K-step; next-step
// global_load_lds issued BEFORE compute so the implicit vmcnt(0) drain at the
// barrier lands after the MFMA phase (load latency hidden).
// Swizzle: logical k-slot q of row r at physical slot q ^ ((r>>1)&3); on the
// staging side this reduces to the lane-constant (lane&3)^((lane>>3)&3).
// Epilogue: upper-tile store + LDS-aggregated candidate extraction (1 global
// atomic per non-empty list). Packed entry: (f16val<<16)|(col^0xFFF).
__global__ __launch_bounds__(256) void gemm_sym(const u16* __restrict__ xh,
                                                u16* __restrict__ simb,
                                                uint32_t* __restrict__ cnt,
                                                uint32_t* __restrict__ lists) {
  __shared__ __align__(16) u16 lds[2 * 2 * 128 * 32];   // 32 KB; epilogue reuses as cand agg
  int b = blockIdx.y;
  int p0 = blockIdx.x;
  int p = (p0 & 7) * 66 + (p0 >> 3);   // bijective XCD swizzle (528 = 8*66)
  const int T = Nn / 128;
  int ti = 0;
  while (p >= T - ti) { p -= T - ti; ti++; }
  int tj = ti + p;
  int ri0 = ti * 128, rj0 = tj * 128;
  int tid = threadIdx.x, wid = tid >> 6, lane = tid & 63;
  int wr = (wid >> 1) * 64, wc = (wid & 1) * 64;   // wave's 64x64 quadrant
  int frow = lane & 15, kg = lane >> 4;            // kg in 0..3 (8-elem k-slot)

  // staging role: tile = wid>>1 (0=A rows@ri0, 1=B rows@rj0), half = wid&1
  int tile = wid >> 1, half = wid & 1;
  int rbase = tile ? rj0 : ri0;
  int q = (lane & 3) ^ ((lane >> 3) & 3);          // logical k-slot this lane fetches
  const u16* sb = xh + ((size_t)b * Nn + rbase + half * 64 + (lane >> 2)) * Dd + q * 8;
  int tbase = tile * 4096 + half * 2048;           // u16 index; HW adds lane*8 u16

  f32x4 acc[4][4];
#pragma unroll
  for (int mt = 0; mt < 4; mt++)
#pragma unroll
    for (int nt = 0; nt < 4; nt++) acc[mt][nt] = (f32x4){0.f, 0.f, 0.f, 0.f};

  // prologue: stage K-step 0 into buf 0
#pragma unroll
  for (int i = 0; i < 4; i++)
    __builtin_amdgcn_global_load_lds((gbl_as*)(sb + (size_t)i * 16 * Dd),
                                     (lds_as*)&lds[tbase + i * 512], 16, 0, 0);
  __syncthreads();

  int cur = 0;
  for (int ks = 0; ks < 16; ks++) {
    if (ks < 15) {   // issue next-step loads first; they fly under the MFMA phase
      const u16* s2 = sb + (size_t)(ks + 1) * 32;
#pragma unroll
      for (int i = 0; i < 4; i++)
        __builtin_amdgcn_global_load_lds((gbl_as*)(s2 + (size_t)i * 16 * Dd),
                                         (lds_as*)&lds[(cur ^ 1) * 8192 + tbase + i * 512], 16, 0, 0);
    }
    int cb = cur * 8192;
    f16x8 bfr[4];
#pragma unroll
    for (int nt = 0; nt < 4; nt++) {
      int rB = wc + nt * 16 + frow;
      int ps = kg ^ ((rB >> 1) & 3);
      bfr[nt] = *(const f16x8*)&lds[cb + 4096 + rB * 32 + ps * 8];
    }
#pragma unroll
    for (int mt = 0; mt < 4; mt++) {
      int rA = wr + mt * 16 + frow;
      int ps = kg ^ ((rA >> 1) & 3);
      f16x8 af = *(const f16x8*)&lds[cb + rA * 32 + ps * 8];
#pragma unroll
      for (int nt = 0; nt < 4; nt++)
        acc[mt][nt] = __builtin_amdgcn_mfma_f32_16x16x32_f16(af, bfr[nt], acc[mt][nt], 0, 0, 0);
    }
    __syncthreads();   // drains vmcnt (next-step staging) + frees buf cur^1 for reuse
    cur ^= 1;
  }

  // ---- epilogue: upper-tile store + LDS candidate aggregation ----
  uint32_t* cntL = (uint32_t*)lds;            // [256] counters (rows 0-127, cols 128-255)
  uint32_t* candL = (uint32_t*)lds + 256;     // [256][TCAP] packed entries (24.5 KB)
  cntL[tid] = 0;
  __syncthreads();

  u16* ob = simb + (size_t)b * Nn * Nn;
  uint32_t grb = (uint32_t)b * Nn;
  bool offdiag = (ti != tj);
#pragma unroll
  for (int mt = 0; mt < 4; mt++) {
    int R0 = wr + mt * 16 + (lane >> 4) * 4;
    int rowg0 = ri0 + R0;
#pragma unroll
    for (int nt = 0; nt < 4; nt++) {
      int C = wc + nt * 16 + frow;
      int colg = rj0 + C;
      float vv[4] = {acc[mt][nt].x, acc[mt][nt].y, acc[mt][nt].z, acc[mt][nt].w};
#pragma unroll
      for (int e = 0; e < 4; e++) {
        u16 u = f16_of(vv[e]);
        ob[(size_t)(rowg0 + e) * Nn + colg] = u;
        if (vv[e] > TH0) {
          uint32_t s = atomicAdd(&cntL[R0 + e], 1u);
          if (s < TCAP)
            candL[(R0 + e) * TCAP + s] = ((uint32_t)u << 16) | ((uint32_t)colg ^ 0xFFFu);
          if (offdiag) {
            uint32_t s2 = atomicAdd(&cntL[128 + C], 1u);
            if (s2 < TCAP)
              candL[(128 + C) * TCAP + s2] = ((uint32_t)u << 16) | ((uint32_t)(rowg0 + e) ^ 0xFFFu);
          }
        }
      }
    }
  }
  __syncthreads();

  // ---- flush: thread tid owns list tid; one global atomic per non-empty list ----
  {
    uint32_t n = cntL[tid];
    bool isRow = tid < 128;
    if (!isRow && !offdiag) n = 0;           // col-lists unused on diagonal tiles
    if (n) {
      uint32_t grow = grb + (uint32_t)(isRow ? (ri0 + tid) : (rj0 + (tid - 128)));
      uint32_t add = (n > TCAP) ? 100000u : n;   // overflow poisons cnt -> fallback path
      uint32_t base = atomicAdd(&cnt[grow], add);
      uint32_t w = (n > TCAP) ? TCAP : n;
      if (base < CAP) {
        uint32_t lim = CAP - base;
        if (w > lim) w = lim;
        for (uint32_t j = 0; j < w; j++)
          lists[(size_t)grow * CAP + base + j] = candL[tid * TCAP + j];
      }
    }
  }
}

// ---------------- K3: exact rank over candidate list + fp32 band refinement ----------------
__global__ __launch_bounds__(256) void rank_kernel(const uint32_t* __restrict__ cnt,
                                                   const uint32_t* __restrict__ lists,
                                                   const float* __restrict__ x,
                                                   const float* __restrict__ rinv,
                                                   uint32_t* __restrict__ bm,
                                                   uint32_t* __restrict__ flagc,
                                                   uint32_t* __restrict__ flagl) {
  int row = blockIdx.x;   // global row in [0, B*N)
  int t = threadIdx.x;    // 256
  int L = (int)cnt[row];
  if (L < 32 || L > CAP) {            // guarantees violated -> exact fallback
    if (t == 0) { uint32_t p = atomicAdd(flagc, 1u); flagl[p] = (uint32_t)row; }
    return;
  }
  __shared__ uint32_t pk[CAP];
  __shared__ uint32_t sSp;
  __shared__ uint32_t lmask[128];
  __shared__ int red[4];
  __shared__ int bandIdx[128];
  __shared__ float bandV[128];
  __shared__ int bandCnt;
  for (int e = t; e < L; e += 256) pk[e] = lists[(size_t)row * CAP + e];
  if (t < 128) lmask[t] = 0;
  if (t == 0) bandCnt = 0;
  __syncthreads();

  // exact rank; rank-31 packed value is the 32nd largest (val desc, idx asc)
  for (int e = t; e < L; e += 256) {
    uint32_t pe = pk[e];
    int rank = 0;
    for (int q = 0; q < L; q++) rank += (pk[q] > pe) ? 1 : 0;
    if (rank == 31) sSp = pe;
  }
  __syncthreads();
  uint32_t Sp = sSp;
  float Sv = f_of_f16((u16)(Sp >> 16));
  float eb = fmaxf(3e-4f, Sv * 1e-3f);
  float hiT = Sv + eb, loT = Sv - eb;
  if (loT <= TH0 + 2e-3f) {           // band may extend below list threshold -> fallback
    if (t == 0) { uint32_t p = atomicAdd(flagc, 1u); flagl[p] = (uint32_t)row; }
    return;
  }

  // classify list entries
  int aCnt = 0;
  for (int e = t; e < L; e += 256) {
    uint32_t pe = pk[e];
    float v = f_of_f16((u16)(pe >> 16));
    int col = (int)((pe & 0xFFFu) ^ 0xFFFu);
    if (v > hiT) {
      atomicOr(&lmask[col >> 5], 1u << (col & 31));
      aCnt++;
    } else if (v >= loT) {
      int s = atomicAdd(&bandCnt, 1);
      if (s < 128) bandIdx[s] = col;
    }
  }
  for (int o = 32; o > 0; o >>= 1) aCnt += __shfl_down(aCnt, o, 64);
  if ((t & 63) == 0) red[t >> 6] = aCnt;
  __syncthreads();
  int A = red[0] + red[1] + red[2] + red[3];   // robustly above (<=31 by rank invariant)
  int BC = bandCnt; if (BC > 128) BC = 128;
  int need = 32 - A;                            // >=1
  bool heavy = (BC > need);
  if (heavy) {
    // recompute band sims with exact fp32 chain
    const float* xn = x + (size_t)row * Dd;
    float ra = rinv[row];
    int bb = row >> 12;
    const float* xbb = x + ((size_t)bb << 12) * Dd;
    for (int s = t; s < BC; s += 256) {
      int m = bandIdx[s];
      const float* xm = xbb + (size_t)m * Dd;
      float dot = 0.f;
      for (int k = 0; k < Dd; k += 4) {
        float4 a4 = *(const float4*)(xn + k);
        float4 b4 = *(const float4*)(xm + k);
        dot = fmaf(a4.x, b4.x, dot);
        dot = fmaf(a4.y, b4.y, dot);
        dot = fmaf(a4.z, b4.z, dot);
        dot = fmaf(a4.w, b4.w, dot);
      }
      bandV[s] = (dot * ra) * rinv[((size_t)bb << 12) + m];
    }
  }
  __syncthreads();
  if (t == 0) {
    if (!heavy) {
      for (int s = 0; s < BC; s++) {
        int gi = bandIdx[s];
        lmask[gi >> 5] |= 1u << (gi & 31);
      }
    } else {
      for (int s = 0; s < need; s++) {   // top-need by (value desc, index asc)
        float bv = -1e30f; int bidx = 0x7FFFFFFF, bs = -1;
        for (int q = 0; q < BC; q++) {
          int gi = bandIdx[q];
          if (gi < 0) continue;
          float v = bandV[q];
          if (v > bv || (v == bv && gi < bidx)) { bv = v; bidx = gi; bs = q; }
        }
        if (bs < 0) break;
        bandIdx[bs] = -1;
        lmask[bidx >> 5] |= 1u << (bidx & 31);
      }
    }
  }
  __syncthreads();
  if (t < 128) bm[(size_t)row * 128 + t] = lmask[t];
}

// ---------------- K3b: exact fp32 fallback for flagged rows (normally empty) ----------------
__global__ __launch_bounds__(256) void fallback_kernel(const uint32_t* __restrict__ flagc,
                                                       const uint32_t* __restrict__ flagl,
                                                       const float* __restrict__ x,
                                                       const float* __restrict__ rinv,
                                                       uint32_t* __restrict__ bm) {
  __shared__ float sv[Nn];            // 16 KB
  __shared__ uint32_t lmask[128];
  __shared__ float wbV[4];
  __shared__ int wbI[4];
  int nf = (int)flagc[0];
  int t = threadIdx.x;
  for (int f = blockIdx.x; f < nf; f += gridDim.x) {
    int row = (int)flagl[f];
    int bb = row >> 12;
    const float* xr = x + (size_t)row * Dd;
    const float* xb = x + ((size_t)bb << 12) * Dd;
    float ra = rinv[row];
    if (t < 128) lmask[t] = 0;
    for (int j = t; j < Nn; j += 256) {
      const float* xj = xb + (size_t)j * Dd;
      float dot = 0.f;
      for (int k = 0; k < Dd; k += 4) {
        float4 a4 = *(const float4*)(xr + k);
        float4 b4 = *(const float4*)(xj + k);
        dot = fmaf(a4.x, b4.x, dot);
        dot = fmaf(a4.y, b4.y, dot);
        dot = fmaf(a4.z, b4.z, dot);
        dot = fmaf(a4.w, b4.w, dot);
      }
      sv[j] = (dot * ra) * rinv[((size_t)bb << 12) + j];
    }
    __syncthreads();
    for (int r = 0; r < 32; r++) {     // 32 rounds of block argmax (val desc, idx asc)
      float bv = -1e30f; int bi = Nn;
      for (int j = t; j < Nn; j += 256) {
        float v = sv[j];
        if (v > bv || (v == bv && j < bi)) { bv = v; bi = j; }
      }
      for (int o = 32; o > 0; o >>= 1) {
        float ov = __shfl_down(bv, o, 64);
        int oi = __shfl_down(bi, o, 64);
        if (ov > bv || (ov == bv && oi < bi)) { bv = ov; bi = oi; }
      }
      if ((t & 63) == 0) { wbV[t >> 6] = bv; wbI[t >> 6] = bi; }
      __syncthreads();
      if (t == 0) {
        float fv = wbV[0]; int fi = wbI[0];
        for (int w = 1; w < 4; w++)
          if (wbV[w] > fv || (wbV[w] == fv && wbI[w] < fi)) { fv = wbV[w]; fi = wbI[w]; }
        sv[fi] = -2e30f;
        lmask[fi >> 5] |= 1u << (fi & 31);
      }
      __syncthreads();
    }
    if (t < 128) bm[(size_t)row * 128 + t] = lmask[t];
    __syncthreads();
  }
}

// ---------------- K4: masked symmetrize, fp16 sim -> fp32 out; exact 1.0 diagonal ----------------
__global__ __launch_bounds__(256) void finalize_kernel(const u16* __restrict__ simb,
                                                       float* __restrict__ out,
                                                       const uint32_t* __restrict__ bm) {
  __shared__ float Tt[64][65];
  __shared__ uint32_t kA[64][2], kB[64][2];
  int b = blockIdx.y;
  int p = blockIdx.x;             // 0..2079 (T=64)
  const int T = Nn / 64;
  int ti = 0;
  while (p >= T - ti) { p -= T - ti; ti++; }
  int tj = ti + p;
  int ri0 = ti * 64, rj0 = tj * 64;
  int t = threadIdx.x;
  const uint32_t* bmb = bm + (size_t)b * Nn * 128;
  if (t < 128) {
    kA[t >> 1][t & 1] = bmb[(size_t)(ri0 + (t >> 1)) * 128 + (rj0 >> 5) + (t & 1)];
  } else {
    int tt = t - 128;
    kB[tt >> 1][tt & 1] = bmb[(size_t)(rj0 + (tt >> 1)) * 128 + (ri0 >> 5) + (tt & 1)];
  }
  __syncthreads();
  const u16* sbase = simb + (size_t)b * Nn * Nn;
  float* ob = out + (size_t)b * Nn * Nn;
  bool diag = (ti == tj);
#pragma unroll
  for (int it = 0; it < 2; it++) {
    int pq = it * 256 + t;          // 512 ushort8-units in the 64x64 tile
    int nl = pq >> 3;
    int ml = (pq & 7) * 8;
    uint4 u = *(const uint4*)(sbase + (size_t)(ri0 + nl) * Nn + rj0 + ml);
    float s0 = f_of_f16((u16)(u.x & 0xFFFFu)), s1 = f_of_f16((u16)(u.x >> 16));
    float s2 = f_of_f16((u16)(u.y & 0xFFFFu)), s3 = f_of_f16((u16)(u.y >> 16));
    float s4 = f_of_f16((u16)(u.z & 0xFFFFu)), s5 = f_of_f16((u16)(u.z >> 16));
    float s6 = f_of_f16((u16)(u.w & 0xFFFFu)), s7 = f_of_f16((u16)(u.w >> 16));
    if (diag) {
      int d = nl - ml;   // element d of this chunk is the exact diagonal (sim(i,i)=1)
      s0 = (d == 0) ? 1.0f : s0;
      s1 = (d == 1) ? 1.0f : s1;
      s2 = (d == 2) ? 1.0f : s2;
      s3 = (d == 3) ? 1.0f : s3;
      s4 = (d == 4) ? 1.0f : s4;
      s5 = (d == 5) ? 1.0f : s5;
      s6 = (d == 6) ? 1.0f : s6;
      s7 = (d == 7) ? 1.0f : s7;
    }
    uint32_t ka = kA[nl][ml >> 5] >> (ml & 31);   // 8 bits, same word (ml%32 in {0,8,16,24})
    uint32_t nw = nl >> 5, nb = nl & 31;
    float4 v0, v1;
    v0.x = 0.5f * s0 * (float)(((ka >> 0) & 1u) + ((kB[ml + 0][nw] >> nb) & 1u));
    v0.y = 0.5f * s1 * (float)(((ka >> 1) & 1u) + ((kB[ml + 1][nw] >> nb) & 1u));
    v0.z = 0.5f * s2 * (float)(((ka >> 2) & 1u) + ((kB[ml + 2][nw] >> nb) & 1u));
    v0.w = 0.5f * s3 * (float)(((ka >> 3) & 1u) + ((kB[ml + 3][nw] >> nb) & 1u));
    v1.x = 0.5f * s4 * (float)(((ka >> 4) & 1u) + ((kB[ml + 4][nw] >> nb) & 1u));
    v1.y = 0.5f * s5 * (float)(((ka >> 5) & 1u) + ((kB[ml + 5][nw] >> nb) & 1u));
    v1.z = 0.5f * s6 * (float)(((ka >> 6) & 1u) + ((kB[ml + 6][nw] >> nb) & 1u));
    v1.w = 0.5f * s7 * (float)(((ka >> 7) & 1u) + ((kB[ml + 7][nw] >> nb) & 1u));
    size_t addr = (size_t)(ri0 + nl) * Nn + rj0 + ml;
    *(float4*)(ob + addr) = v0;
    *(float4*)(ob + addr + 4) = v1;
    Tt[ml + 0][nl] = v0.x; Tt[ml + 1][nl] = v0.y; Tt[ml + 2][nl] = v0.z; Tt[ml + 3][nl] = v0.w;
    Tt[ml + 4][nl] = v1.x; Tt[ml + 5][nl] = v1.y; Tt[ml + 6][nl] = v1.z; Tt[ml + 7][nl] = v1.w;
  }
  if (ti != tj) {
    __syncthreads();
#pragma unroll
    for (int it = 0; it < 4; it++) {
      int pq = it * 256 + t;
      int nl = pq >> 4;
      int ml = (pq & 15) << 2;
      float4 v;
      v.x = Tt[nl][ml + 0]; v.y = Tt[nl][ml + 1];
      v.z = Tt[nl][ml + 2]; v.w = Tt[nl][ml + 3];
      *(float4*)(ob + (size_t)(rj0 + nl) * Nn + ri0 + ml) = v;
    }
  }
}

extern "C" void kernel_launch(void* const* d_in, const int* in_sizes, int n_in,
                              void* d_out, int out_size, void* d_ws, size_t ws_size,
                              hipStream_t stream) {
  const float* x = (const float*)d_in[0];
  float* out = (float*)d_out;
  // ws layout (16B-aligned):
  // rinv 64KB | bm 8MB | xh 16MB | simb 128MB | cnt 64KB | flagc 256B | flagl 64KB | lists 32MB
  char* base = (char*)d_ws;
  float* rinv = (float*)base;
  uint32_t* bm = (uint32_t*)(base + (1u << 16));
  u16* xh = (u16*)(base + (1u << 16) + (8u << 20));
  u16* simb = xh + (size_t)Bsz * Nn * Dd;
  uint32_t* cnt = (uint32_t*)((char*)simb + (size_t)Bsz * Nn * Nn * 2);
  uint32_t* flagc = cnt + (size_t)Bsz * Nn;
  uint32_t* flagl = flagc + 64;
  uint32_t* lists = flagl + (size_t)Bsz * Nn;

  prep_kernel<<<Bsz * Nn, 128, 0, stream>>>(x, rinv, xh, cnt, flagc);
  dim3 g2(528, Bsz);
  gemm_sym<<<g2, 256, 0, stream>>>(xh, simb, cnt, lists);
  rank_kernel<<<Bsz * Nn, 256, 0, stream>>>(cnt, lists, x, rinv, bm, flagc, flagl);
  fallback_kernel<<<64, 256, 0, stream>>>(flagc, flagl, x, rinv, bm);
  dim3 g4(2080, Bsz);
  finalize_kernel<<<g4, 256, 0, stream>>>(simb, out, bm);
}